// Round 13
// baseline (298.624 us; speedup 1.0000x reference)
//
#include <hip/hip_runtime.h>
#include <hip/hip_bf16.h>

#define BB 2048
#define TT 128
#define NN (BB*TT)          // 262144
#define NVAL NN

// workspace layout (float offsets)
#define OFF_W0P   2048u       // W0 A-frag pack (16384 bf16)
#define OFF_W1P   10240u      // W1 A-frag pack, k-permuted (65536 bf16)
#define OFF_WQKV  43008u      // attn_in_w B-frag pack
#define OFF_WO    44544u      // attn_out_w B-frag pack
#define OFF_PWHA  49792u      // air Whh f16 A-frag pack (perm rows, exp2-scaled): 1536 uints
#define OFF_PWHM  51328u      // m   Whh f16 A-frag pack: 1536 uints
#define OFF_PWCA  52864u      // air combined Wih f16 A-frag pack (+bias col): 1536 uints
#define OFF_PWCM  54400u      // m   combined Wih f16 A-frag pack: 1536 uints
#define OFF_BHNA  55936u      // air bhh n-gate (32 f32, x 2*log2e)
#define OFF_BHNM  55968u      // m   bhh n-gate (32 f32)
#define OFF_AIRF  83968u      // air_feat bf16: NN*32 shorts = 4194304 floats
#define OFF_MF    4278272u    // m_feat bf16: 2*NN*32 shorts = 8388608 floats
#define OFF_MASK  12666880u   // N*2 mask floats

#define L2E 1.44269504088896341f

typedef __attribute__((ext_vector_type(8))) short short8;
typedef __attribute__((ext_vector_type(4))) float f32x4;
typedef _Float16 f16x8 __attribute__((ext_vector_type(8)));
typedef unsigned u32x4 __attribute__((ext_vector_type(4)));

__device__ __forceinline__ unsigned short f2bf(float f) {
    unsigned u = __builtin_bit_cast(unsigned, f);
    u += 0x7FFFu + ((u >> 16) & 1u);       // RNE
    return (unsigned short)(u >> 16);
}
__device__ __forceinline__ unsigned f2h(float f) {
    _Float16 h = (_Float16)f;
    return (unsigned)__builtin_bit_cast(unsigned short, h);
}
__device__ __forceinline__ unsigned pkh2(float a, float b) {
    return (f2h(b) << 16) | f2h(a);
}
__device__ __forceinline__ float fast_rcp(float x) {
    return __builtin_amdgcn_rcpf(x);
}
__device__ __forceinline__ float ex2(float x) {
    return __builtin_amdgcn_exp2f(x);
}
__device__ __forceinline__ unsigned cvt_pk_bf16(float a, float b) {
    unsigned r;
    asm("v_cvt_pk_bf16_f32 %0, %1, %2" : "=v"(r) : "v"(a), "v"(b));
    return r;
}
__device__ __forceinline__ f32x4 mfma16f(f16x8 a, f16x8 b, f32x4 c) {
    return __builtin_amdgcn_mfma_f32_16x16x32_f16(a, b, c, 0, 0, 0);
}
__device__ __forceinline__ f32x4 mfma16b(short8 a, short8 b, f32x4 c) {
    return __builtin_amdgcn_mfma_f32_16x16x32_bf16(a, b, c, 0, 0, 0);
}
__device__ __forceinline__ float lrelu(float h) {
    return (h > 0.f) ? h : 0.01f*h;
}

// ---------------- prep (GRU packs only; fused packs moved into gru) ---------
__global__ __launch_bounds__(256) void prep_kernel(
    const float* __restrict__ enc_air_W, const float* __restrict__ enc_air_b,
    const float* __restrict__ enc_m_W,   const float* __restrict__ enc_m_b,
    const float* __restrict__ air_Wih,   const float* __restrict__ air_bih,
    const float* __restrict__ m_Wih,     const float* __restrict__ m_bih,
    const float* __restrict__ air_Whh,   const float* __restrict__ m_Whh,
    const float* __restrict__ air_bhh,   const float* __restrict__ m_bhh,
    float* __restrict__ ws)
{
    int b = blockIdx.x, t = threadIdx.x;
    if (b == 0) {
        // Whh f16 A-frag packs (exp2-prescaled: r,z x log2e; n x 2*log2e).
        unsigned* pa = (unsigned*)(ws + OFF_PWHA);
        unsigned* pm = (unsigned*)(ws + OFF_PWHM);
        for (int s = t; s < 3072; s += 256) {
            int s2 = (s < 1536) ? s : s - 1536;
            const float* W = (s < 1536) ? air_Whh : m_Whh;
            unsigned* dst = (s < 1536) ? pa : pm;
            int tile = s2 >> 8;          // 0..5
            int l    = (s2 >> 2) & 63;
            int d    = s2 & 3;           // dword within frag
            int gate = tile >> 1, hfp = tile & 1;
            int rr = l & 15;
            int f  = (rr >> 2)*8 + hfp*4 + (rr & 3);
            int k  = (l >> 4)*8 + d*2;
            int row = gate*32 + f;
            float sc = (gate == 2) ? 2.f*L2E : L2E;
            dst[s2] = pkh2(W[row*32 + k]*sc, W[row*32 + k + 1]*sc);
        }
    } else { // b == 1: combined input-weight f16 A-frags (+bias col), exp2-prescaled
        unsigned* pa = (unsigned*)(ws + OFF_PWCA);
        unsigned* pm = (unsigned*)(ws + OFF_PWCM);
        for (int s = t; s < 3072; s += 256) {
            bool isA = (s < 1536);
            int s2 = isA ? s : s - 1536;
            unsigned* dst = isA ? pa : pm;
            int tile = s2 >> 8, l = (s2 >> 2) & 63, d = s2 & 3;
            int gate = tile >> 1, hfp = tile & 1;
            int rr = l & 15;
            int f = (rr >> 2)*8 + hfp*4 + (rr & 3);
            int o = gate*32 + f;
            int kb = (l >> 4)*8 + d*2;
            int ni = isA ? 7 : 4;
            float sc = (gate == 2) ? 2.f*L2E : L2E;
            float v[2];
            #pragma unroll
            for (int e = 0; e < 2; e++) {
                int k = kb + e;
                float acc = 0.f;
                if (k < ni) {
                    for (int m = 0; m < 32; m++)
                        acc += isA ? air_Wih[o*32+m]*enc_air_W[m*7+k]
                                   : m_Wih[o*32+m]*enc_m_W[m*4+k];
                } else if (k == ni) {
                    acc = isA ? air_bih[o] : m_bih[o];
                    for (int m = 0; m < 32; m++)
                        acc += isA ? air_Wih[o*32+m]*enc_air_b[m]
                                   : m_Wih[o*32+m]*enc_m_b[m];
                    if (gate < 2) acc += isA ? air_bhh[o] : m_bhh[o]; // r,z: fold bhh
                }
                v[e] = acc*sc;
            }
            dst[s2] = pkh2(v[0], v[1]);
        }
        if (t < 32) {
            ws[OFF_BHNA + t] = air_bhh[64 + t]*2.f*L2E;
            ws[OFF_BHNM + t] = m_bhh[64 + t]*2.f*L2E;
        }
    }
}

// ---------------- GRU v7 (best measured): 2x-unrolled serial loop -----------
template<bool AIRT>
__device__ __forceinline__ void gru_tile(
    const float* __restrict__ obs, const float* __restrict__ rnn,
    const float* __restrict__ ws,
    unsigned short* __restrict__ feat, float* __restrict__ mask_f,
    float* __restrict__ nh_out, int tileIdx, unsigned* __restrict__ XH)
{
    const int lane = threadIdx.x & 63;
    const int col = lane & 15, quad = lane >> 4;

    const unsigned* pw = (const unsigned*)(ws + (AIRT ? OFF_PWHA : OFF_PWHM));
    const unsigned* pc = (const unsigned*)(ws + (AIRT ? OFF_PWCA : OFF_PWCM));
    f16x8 whf[6], wcf[6];
    #pragma unroll
    for (int i6 = 0; i6 < 6; i6++) {
        whf[i6] = __builtin_bit_cast(f16x8, *(const u32x4*)(pw + i6*256 + lane*4));
        wcf[i6] = __builtin_bit_cast(f16x8, *(const u32x4*)(pc + i6*256 + lane*4));
    }
    const float* bhnp = ws + (AIRT ? OFF_BHNA : OFF_BHNM) + quad*8;
    f32x4 bhn0 = *(const f32x4*)(bhnp);
    f32x4 bhn1 = *(const f32x4*)(bhnp + 4);

    int slot = 0, tb;
    if (AIRT) { tb = tileIdx*16; }
    else      { slot = tileIdx >> 7; tb = (tileIdx & 127)*16; }

    {
        const int coff = AIRT ? 8 : slot*4;
        #pragma unroll 4
        for (int it = 0; it < 32; it++) {
            int s = it*64 + lane;
            int r = s >> 7, t = s & 127;
            const float* p = obs + (size_t)(tb + r)*1920 + t*15 + coff;
            unsigned d0, d1, d2, d3;
            if (AIRT) {
                d0 = pkh2(p[0], p[1]); d1 = pkh2(p[2], p[3]);
                d2 = pkh2(p[4], p[5]); d3 = pkh2(p[6], 1.0f);
            } else {
                float x0 = p[0], x1 = p[1], x2 = p[2], x3 = p[3];
                d0 = pkh2(x0, x1); d1 = pkh2(x2, x3);
                d2 = 0x00003C00u; d3 = 0u;     // (1.0h, 0) bias col
                bool ok = (fabsf(x0 - 1.f) <= 1.00001e-5f) && (fabsf(x1) <= 1e-8f) &&
                          (fabsf(x2 - 1.f) <= 1.00001e-5f) && (fabsf(x3) <= 1e-8f);
                mask_f[((size_t)(tb + r)*TT + t)*2 + slot] = ok ? 1.f : 0.f;
            }
            unsigned off = (unsigned)(r*512 + 4*(t ^ (r & 7)));   // 16B XOR swizzle
            *(u32x4*)(XH + off) = (u32x4){d0, d1, d2, d3};
        }
    }
    __syncthreads();

    int rowi = tileIdx*16 + col;
    int hbase;
    if (AIRT) hbase = rowi*96;
    else      hbase = (rowi >> 1)*96 + 32 + (rowi & 1)*32;
    unsigned short* featp = feat + (size_t)rowi*(TT*32) + quad*8;

    f32x4 h0v = *(const f32x4*)(rnn + hbase + quad*8);
    f32x4 h1v = *(const f32x4*)(rnn + hbase + quad*8 + 4);

    const int xk = col & 7;
    const unsigned bidx = (unsigned)col*512;
    const f32x4 z4 = {0.f, 0.f, 0.f, 0.f};

    f32x4 gx0, gx1, gx2, gx3, gx4, gx5;
    {
        u32x4 xc = *(const u32x4*)(XH + bidx + 4u*(unsigned)(0 ^ xk));
        f16x8 xf = __builtin_bit_cast(f16x8, xc);
        gx0 = mfma16f(wcf[0], xf, z4); gx1 = mfma16f(wcf[1], xf, z4);
        gx2 = mfma16f(wcf[2], xf, z4); gx3 = mfma16f(wcf[3], xf, z4);
        gx4 = mfma16f(wcf[4], xf, z4); gx5 = mfma16f(wcf[5], xf, z4);
    }
    u32x4 xA = *(const u32x4*)(XH + bidx + 4u*(unsigned)(1 ^ xk));
    u32x4 xB = *(const u32x4*)(XH + bidx + 4u*(unsigned)(2 ^ xk));

    #pragma unroll 1
    for (int t = 0; t < TT; t += 2) {
        f32x4 gy0, gy1, gy2, gy3, gy4, gy5;
        {
            u32x4 hdv;
            hdv[0] = pkh2(h0v[0], h0v[1]); hdv[1] = pkh2(h0v[2], h0v[3]);
            hdv[2] = pkh2(h1v[0], h1v[1]); hdv[3] = pkh2(h1v[2], h1v[3]);
            f16x8 hff = __builtin_bit_cast(f16x8, hdv);

            f32x4 aR0 = mfma16f(whf[0], hff, gx0);
            f32x4 aR1 = mfma16f(whf[1], hff, gx1);
            f32x4 aZ0 = mfma16f(whf[2], hff, gx2);
            f32x4 aZ1 = mfma16f(whf[3], hff, gx3);
            f32x4 aHN0 = mfma16f(whf[4], hff, bhn0);
            f32x4 aHN1 = mfma16f(whf[5], hff, bhn1);
            f32x4 aXN0 = gx4, aXN1 = gx5;

            f16x8 xf1 = __builtin_bit_cast(f16x8, xA);
            gy0 = mfma16f(wcf[0], xf1, z4); gy1 = mfma16f(wcf[1], xf1, z4);
            gy2 = mfma16f(wcf[2], xf1, z4); gy3 = mfma16f(wcf[3], xf1, z4);
            gy4 = mfma16f(wcf[4], xf1, z4); gy5 = mfma16f(wcf[5], xf1, z4);
            const int tp = (t+3 < TT) ? t+3 : TT-1;
            xA = *(const u32x4*)(XH + bidx + 4u*(unsigned)(tp ^ xk));

            #pragma unroll
            for (int s = 0; s < 4; s++) {
                {
                    float r = fast_rcp(1.f + ex2(-aR0[s]));
                    float z = fast_rcp(1.f + ex2(-aZ0[s]));
                    float p = aXN0[s] + r*aHN0[s];
                    float n = fmaf(-2.f, fast_rcp(1.f + ex2(p)), 1.f);
                    h0v[s] = n + z*(h0v[s] - n);
                }
                {
                    float r = fast_rcp(1.f + ex2(-aR1[s]));
                    float z = fast_rcp(1.f + ex2(-aZ1[s]));
                    float p = aXN1[s] + r*aHN1[s];
                    float n = fmaf(-2.f, fast_rcp(1.f + ex2(p)), 1.f);
                    h1v[s] = n + z*(h1v[s] - n);
                }
            }

            u32x4 fwE;
            fwE[0] = cvt_pk_bf16(h0v[0], h0v[1]); fwE[1] = cvt_pk_bf16(h0v[2], h0v[3]);
            fwE[2] = cvt_pk_bf16(h1v[0], h1v[1]); fwE[3] = cvt_pk_bf16(h1v[2], h1v[3]);
            *(u32x4*)(featp + (size_t)t*32) = fwE;
        }
        {
            u32x4 hdv2;
            hdv2[0] = pkh2(h0v[0], h0v[1]); hdv2[1] = pkh2(h0v[2], h0v[3]);
            hdv2[2] = pkh2(h1v[0], h1v[1]); hdv2[3] = pkh2(h1v[2], h1v[3]);
            f16x8 hff2 = __builtin_bit_cast(f16x8, hdv2);

            f32x4 bR0 = mfma16f(whf[0], hff2, gy0);
            f32x4 bR1 = mfma16f(whf[1], hff2, gy1);
            f32x4 bZ0 = mfma16f(whf[2], hff2, gy2);
            f32x4 bZ1 = mfma16f(whf[3], hff2, gy3);
            f32x4 bHN0 = mfma16f(whf[4], hff2, bhn0);
            f32x4 bHN1 = mfma16f(whf[5], hff2, bhn1);
            f32x4 bXN0 = gy4, bXN1 = gy5;

            f16x8 xf2 = __builtin_bit_cast(f16x8, xB);
            gx0 = mfma16f(wcf[0], xf2, z4); gx1 = mfma16f(wcf[1], xf2, z4);
            gx2 = mfma16f(wcf[2], xf2, z4); gx3 = mfma16f(wcf[3], xf2, z4);
            gx4 = mfma16f(wcf[4], xf2, z4); gx5 = mfma16f(wcf[5], xf2, z4);
            const int tq = (t+4 < TT) ? t+4 : TT-1;
            xB = *(const u32x4*)(XH + bidx + 4u*(unsigned)(tq ^ xk));

            #pragma unroll
            for (int s = 0; s < 4; s++) {
                {
                    float r = fast_rcp(1.f + ex2(-bR0[s]));
                    float z = fast_rcp(1.f + ex2(-bZ0[s]));
                    float p = bXN0[s] + r*bHN0[s];
                    float n = fmaf(-2.f, fast_rcp(1.f + ex2(p)), 1.f);
                    h0v[s] = n + z*(h0v[s] - n);
                }
                {
                    float r = fast_rcp(1.f + ex2(-bR1[s]));
                    float z = fast_rcp(1.f + ex2(-bZ1[s]));
                    float p = bXN1[s] + r*bHN1[s];
                    float n = fmaf(-2.f, fast_rcp(1.f + ex2(p)), 1.f);
                    h1v[s] = n + z*(h1v[s] - n);
                }
            }

            u32x4 fwO;
            fwO[0] = cvt_pk_bf16(h0v[0], h0v[1]); fwO[1] = cvt_pk_bf16(h0v[2], h0v[3]);
            fwO[2] = cvt_pk_bf16(h1v[0], h1v[1]); fwO[3] = cvt_pk_bf16(h1v[2], h1v[3]);
            *(u32x4*)(featp + (size_t)(t+1)*32) = fwO;
        }
    }
    *(f32x4*)(nh_out + hbase + quad*8)     = h0v;
    *(f32x4*)(nh_out + hbase + quad*8 + 4) = h1v;
}

// gru launch: blocks 0-383 run GRU tiles; blocks 384-424 build the FUSED
// weight packs (independent of GRU packs) concurrently, hiding the old
// serial prep time in gru's shadow.
__global__ __launch_bounds__(64, 1) void gru_kernel(
    const float* __restrict__ obs, const float* __restrict__ rnn,
    const float* __restrict__ ws,
    unsigned short* __restrict__ air_feat, unsigned short* __restrict__ m_feat,
    float* __restrict__ mask_f, float* __restrict__ nh_out,
    const float* __restrict__ W0, const float* __restrict__ W1,
    const float* __restrict__ attn_in_w, const float* __restrict__ attn_out_w,
    float* __restrict__ wsw)
{
    __shared__ unsigned XH[8192];   // 16 rows x 128 t x 4 dwords
    int g = blockIdx.x;
    if (g < 128) { gru_tile<true >(obs, rnn, ws, air_feat, mask_f, nh_out, g, XH); return; }
    if (g < 384) { gru_tile<false>(obs, rnn, ws, m_feat,  mask_f, nh_out, g - 128, XH); return; }

    int pb = g - 384;                    // 0..40 (old prep blocks 1..41)
    if (pb < 32) {
        // W1 A-frag pack, K-PERMUTED
        unsigned short* w1p = (unsigned short*)(wsw + OFF_W1P);
        for (int tt = threadIdx.x; tt < 256; tt += 64) {
            int base = pb*256 + tt;
            int lane = base & 63;
            int ctf  = base >> 6;           // 0..127
            int ft2  = ctf & 15, kap = ctf >> 4;
            int col = lane & 15, quad = lane >> 4;
            int o  = ft2*16 + col;
            #pragma unroll
            for (int j = 0; j < 8; j++) {
                int f = (2*kap + (j>>2))*16 + quad*4 + (j&3);
                w1p[base*8 + j] = f2bf(W1[o*256 + f]);
            }
        }
    } else if (pb < 40) {
        // W0 A-frag pack (natural)
        unsigned short* w0p = (unsigned short*)(wsw + OFF_W0P);
        for (int tt = threadIdx.x; tt < 256; tt += 64) {
            int base = (pb-32)*256 + tt;
            int lane = base & 63;
            int ctf  = base >> 6;
            int ct   = ctf & 15, s = ctf >> 4;   // s 0..1
            int col = lane & 15, quad = lane >> 4;
            int k0 = s*32 + quad*8;
            int o  = ct*16 + col;
            #pragma unroll
            for (int j = 0; j < 8; j++)
                w0p[base*8 + j] = f2bf(W0[o*64 + k0 + j]);
        }
    } else {
        // attention weight packs
        unsigned short* wqkv = (unsigned short*)(wsw + OFF_WQKV);
        unsigned short* wop  = (unsigned short*)(wsw + OFF_WO);
        for (int slot = threadIdx.x; slot < 512; slot += 64) {
            if (slot < 384) {
                int ct = slot >> 6, lane = slot & 63;
                int col = lane & 15, quad = lane >> 4;
                int o = ct*16 + col;
                #pragma unroll
                for (int j = 0; j < 8; j++)
                    wqkv[slot*8 + j] = f2bf(attn_in_w[o*32 + quad*8 + j]);
            } else {
                int s2 = slot - 384;
                int ct = s2 >> 6, lane = s2 & 63;
                int col = lane & 15, quad = lane >> 4;
                #pragma unroll
                for (int j = 0; j < 8; j++)
                    wop[s2*8 + j] = f2bf(attn_out_w[(ct*16+col)*32 + quad*8 + j]);
            }
        }
    }
}

// ---------------- fused v9 (best measured): v6 structure + sigmoid softmax --
__global__ __launch_bounds__(512, 6) void fused_kernel(
    const unsigned short* __restrict__ air_feat, const unsigned short* __restrict__ m_feat,
    const float* __restrict__ mask_f,
    const unsigned short* __restrict__ wqkv, const float* __restrict__ attn_in_b,
    const unsigned short* __restrict__ wop,  const float* __restrict__ attn_out_b,
    const unsigned short* __restrict__ w0p, const float* __restrict__ b0,
    const unsigned short* __restrict__ w1p, const float* __restrict__ b1,
    const float* __restrict__ outW, const float* __restrict__ outb,
    float* __restrict__ val)
{
    __shared__ unsigned short XB[16384];   // 32KB: l2 B-frags; CT aliases (phase1)
    __shared__ unsigned short ATPS[4096];  // 8KB: AT (phase2); PS aliases (out)

    unsigned short* CT = XB;               // attn ctx transpose (phase1 only)
    unsigned short* AT = ATPS;
    float* PS = (float*)ATPS;              // [8][64] floats, AT dead by then

    const int tid  = threadIdx.x;
    const int lane = tid & 63;
    const int wid  = tid >> 6;             // 0..7
    const int col  = lane & 15;
    const int quad = lane >> 4;
    const size_t n0 = (size_t)blockIdx.x * 64;
    const int strip = wid >> 1;            // attention strip (0..3)
    const int act   = wid & 1;             // attention ct column (0..1)
    const int rt    = wid & 3;             // l1 row-tile
    const int tbase = (wid >> 2) * 8;      // l1's 8 W0 feature-tiles

    const f32x4 z4 = {0.f, 0.f, 0.f, 0.f};
    const float C1 = 0.25f*L2E;            // score scale x log2e
    const float MB = 1e9f*L2E;             // mask magnitude x log2e

    // ---- attention: one (strip, ct) per wave; sigmoid-form 2-key softmax ---
    {
        short8 wq = *(const short8*)(wqkv + ((0+act)*64 + lane)*8);
        short8 wk = *(const short8*)(wqkv + ((2+act)*64 + lane)*8);
        short8 wv = *(const short8*)(wqkv + ((4+act)*64 + lane)*8);
        short8 bAirA = *(const short8*)(air_feat + (n0 + strip*16 + col)*32 + quad*8);
        short8 a_m1 = *(const short8*)(m_feat + (n0 + strip*16 + col)*32 + quad*8);
        short8 a_m2 = *(const short8*)(m_feat + ((size_t)NN + n0 + strip*16 + col)*32 + quad*8);

        f32x4 q  = mfma16b(bAirA, wq, z4);
        f32x4 k1 = mfma16b(a_m1, wk, z4);
        f32x4 k2 = mfma16b(a_m2, wk, z4);
        f32x4 v1 = mfma16b(a_m1, wv, z4);
        f32x4 v2 = mfma16b(a_m2, wv, z4);
        float bq = attn_in_b[act*16 + col];
        float bk = attn_in_b[32 + act*16 + col];
        float bv = attn_in_b[64 + act*16 + col];

        #pragma unroll
        for (int reg = 0; reg < 4; reg++) {
            float qq = q[reg] + bq;
            float p1 = qq * (k1[reg] + bk);
            float p2 = qq * (k2[reg] + bk);
            #pragma unroll
            for (int m = 1; m < 16; m <<= 1) {
                p1 += __shfl_xor(p1, m, 64);
                p2 += __shfl_xor(p2, m, 64);
            }
            const float* mp = mask_f + (size_t)(n0 + strip*16 + quad*4 + reg)*2;
            float m0v = mp[0], m1v = mp[1];
            // w1 = sigmoid(s1 - s2); masks enter via the difference
            float md2 = (m0v > 0.5f ? -MB : 0.f) - (m1v > 0.5f ? -MB : 0.f);
            float ny = fmaf(p2 - p1, C1, -md2);     // -L2E*(s1-s2)
            float w1 = fast_rcp(1.f + ex2(ny));
            float ctxv = fmaf(v1[reg] - v2[reg], w1, v2[reg] + bv);
            CT[(strip*16 + quad*4 + reg)*40 + act*16 + col] = f2bf(ctxv);
        }
    }
    __syncthreads();   // CT complete

    // ---- phase 2: wo+AT (waves 0-3) / l1-air (waves 4-7) -------------------
    f32x4 accL1[8];
    #pragma unroll
    for (int i = 0; i < 8; i++) accL1[i] = z4;
    short8 w0f0[8];
    #pragma unroll
    for (int i = 0; i < 8; i++)
        w0f0[i] = *(const short8*)(w0p + ((tbase + i)*64 + lane)*8);
    short8 bAirL = *(const short8*)(air_feat + (n0 + rt*16 + col)*32 + quad*8);

    if (wid < 4) {
        short8 wof0 = *(const short8*)(wop + (0*64 + lane)*8);
        short8 wof1 = *(const short8*)(wop + (1*64 + lane)*8);
        short8 a_ctx = *(const short8*)&CT[(wid*16 + col)*40 + quad*8];
        f32x4 ao0 = mfma16b(a_ctx, wof0, z4);
        f32x4 ao1 = mfma16b(a_ctx, wof1, z4);
        float bor0 = attn_out_b[col], bor1 = attn_out_b[16 + col];
        #pragma unroll
        for (int reg = 0; reg < 4; reg++) {
            const float* mp = mask_f + (size_t)(n0 + wid*16 + quad*4 + reg)*2;
            bool both = (mp[0] > 0.5f) && (mp[1] > 0.5f);
            float av0 = both ? 0.f : (ao0[reg] + bor0);
            float av1 = both ? 0.f : (ao1[reg] + bor1);
            AT[wid*1024 + (quad*4 + reg)*64 + col] = f2bf(av0);
            AT[wid*1024 + (quad*4 + reg)*64 + 16 + col] = f2bf(av1);
        }
    } else {
        #pragma unroll
        for (int i = 0; i < 8; i++)
            accL1[i] = mfma16b(w0f0[i], bAirL, accL1[i]);
    }
    __syncthreads();   // AT ready; CT dead -> XB reusable

    // ---- l1 remainder ----
    if (wid < 4) {
        #pragma unroll
        for (int i = 0; i < 8; i++)
            accL1[i] = mfma16b(w0f0[i], bAirL, accL1[i]);
    }
    {
        short8 bAttn = *(const short8*)&AT[rt*1024 + col*64 + quad*8];
        #pragma unroll
        for (int i = 0; i < 8; i++) {
            short8 w0f1 = *(const short8*)(w0p + ((16 + tbase + i)*64 + lane)*8);
            accL1[i] = mfma16b(w0f1, bAttn, accL1[i]);
        }
    }
    // ---- l1 epilogue: bias+leaky+pack -> XB B-frags (linear writes) --------
    #pragma unroll
    for (int i = 0; i < 8; i += 2) {
        int t0 = tbase + i;
        f32x4 bA = *(const f32x4*)(b0 + t0*16 + quad*4);
        f32x4 bB = *(const f32x4*)(b0 + (t0+1)*16 + quad*4);
        float a0 = lrelu(accL1[i][0]   + bA[0]), a1 = lrelu(accL1[i][1]   + bA[1]);
        float a2 = lrelu(accL1[i][2]   + bA[2]), a3 = lrelu(accL1[i][3]   + bA[3]);
        float c0 = lrelu(accL1[i+1][0] + bB[0]), c1 = lrelu(accL1[i+1][1] + bB[1]);
        float c2 = lrelu(accL1[i+1][2] + bB[2]), c3 = lrelu(accL1[i+1][3] + bB[3]);
        u32x4 w;
        w[0] = cvt_pk_bf16(a0, a1); w[1] = cvt_pk_bf16(a2, a3);
        w[2] = cvt_pk_bf16(c0, c1); w[3] = cvt_pk_bf16(c2, c3);
        int kap = t0 >> 1;
        *(u32x4*)((unsigned*)XB + ((rt*8 + kap)*64 + lane)*4) = w;
    }
    __syncthreads();   // XB ready; AT dead after bAttn read above

    // ---- l2: z4 init (v6-proven); wave owns 2 feature-tiles ----------------
    f32x4 acc2[4][2];
    #pragma unroll
    for (int r = 0; r < 4; r++)
        #pragma unroll
        for (int c = 0; c < 2; c++) acc2[r][c] = z4;
    {
        short8 w1f[2], w1n[2];
        #pragma unroll
        for (int c = 0; c < 2; c++)
            w1f[c] = *(const short8*)(w1p + ((0*16 + wid*2 + c)*64 + lane)*8);
        #pragma unroll
        for (int kap = 0; kap < 8; kap++) {
            if (kap < 7) {
                #pragma unroll
                for (int c = 0; c < 2; c++)
                    w1n[c] = *(const short8*)(w1p + (((kap+1)*16 + wid*2 + c)*64 + lane)*8);
            }
            short8 bx[4];
            #pragma unroll
            for (int r = 0; r < 4; r++)
                bx[r] = *(const short8*)&XB[((r*8 + kap)*64 + lane)*8];
            #pragma unroll
            for (int c = 0; c < 2; c++)
                #pragma unroll
                for (int r = 0; r < 4; r++)
                    acc2[r][c] = mfma16b(w1f[c], bx[r], acc2[r][c]);
            #pragma unroll
            for (int c = 0; c < 2; c++) w1f[c] = w1n[c];
        }
    }

    // ---- out layer: b1v/owv loaded after l2 (v6-proven); quad-reduce only --
    f32x4 b1v[2], owv[2];
    #pragma unroll
    for (int c = 0; c < 2; c++) {
        b1v[c] = *(const f32x4*)(b1 + (wid*2 + c)*16 + quad*4);
        owv[c] = *(const f32x4*)(outW + (wid*2 + c)*16 + quad*4);
    }
    const float outb0 = outb[0];
    #pragma unroll
    for (int r = 0; r < 4; r++) {
        float pv = 0.f;
        #pragma unroll
        for (int c = 0; c < 2; c++) {
            #pragma unroll
            for (int reg = 0; reg < 4; reg++) {
                float h = lrelu(acc2[r][c][reg] + b1v[c][reg]);
                pv += h*owv[c][reg];
            }
        }
        pv += __shfl_xor(pv, 16, 64);
        pv += __shfl_xor(pv, 32, 64);
        if (lane < 16) PS[wid*64 + r*16 + lane] = pv;
    }
    __syncthreads();
    if (tid < 64)
        val[n0 + tid] = PS[0*64 + tid] + PS[1*64 + tid] + PS[2*64 + tid] + PS[3*64 + tid]
                      + PS[4*64 + tid] + PS[5*64 + tid] + PS[6*64 + tid] + PS[7*64 + tid] + outb0;
}

// ---------------- launch ---------------------------------------------------
extern "C" void kernel_launch(void* const* d_in, const int* in_sizes, int n_in,
                              void* d_out, int out_size, void* d_ws, size_t ws_size,
                              hipStream_t stream) {
    const float* obs        = (const float*)d_in[0];
    const float* rnn        = (const float*)d_in[1];
    const float* enc_air_W  = (const float*)d_in[2];
    const float* enc_air_b  = (const float*)d_in[3];
    const float* enc_m_W    = (const float*)d_in[4];
    const float* enc_m_b    = (const float*)d_in[5];
    const float* air_Wih    = (const float*)d_in[6];
    const float* air_Whh    = (const float*)d_in[7];
    const float* air_bih    = (const float*)d_in[8];
    const float* air_bhh    = (const float*)d_in[9];
    const float* m_Wih      = (const float*)d_in[10];
    const float* m_Whh      = (const float*)d_in[11];
    const float* m_bih      = (const float*)d_in[12];
    const float* m_bhh      = (const float*)d_in[13];
    const float* attn_in_w  = (const float*)d_in[14];
    const float* attn_in_b  = (const float*)d_in[15];
    const float* attn_out_w = (const float*)d_in[16];
    const float* attn_out_b = (const float*)d_in[17];
    const float* mlp_W0     = (const float*)d_in[18];
    const float* mlp_b0     = (const float*)d_in[19];
    const float* mlp_W1     = (const float*)d_in[20];
    const float* mlp_b1     = (const float*)d_in[21];
    const float* out_W      = (const float*)d_in[22];
    const float* out_b      = (const float*)d_in[23];

    float* ws  = (float*)d_ws;
    float* out = (float*)d_out;

    prep_kernel<<<2, 256, 0, stream>>>(enc_air_W, enc_air_b, enc_m_W, enc_m_b,
                                       air_Wih, air_bih, m_Wih, m_bih,
                                       air_Whh, m_Whh, air_bhh, m_bhh, ws);

    gru_kernel<<<425, 64, 0, stream>>>(obs, rnn, ws,
                                       (unsigned short*)(ws + OFF_AIRF),
                                       (unsigned short*)(ws + OFF_MF),
                                       ws + OFF_MASK, out + NVAL,
                                       mlp_W0, mlp_W1, attn_in_w, attn_out_w, ws);

    fused_kernel<<<NN/64, 512, 0, stream>>>((const unsigned short*)(ws + OFF_AIRF),
                                            (const unsigned short*)(ws + OFF_MF),
                                            ws + OFF_MASK,
                                            (const unsigned short*)(ws + OFF_WQKV), attn_in_b,
                                            (const unsigned short*)(ws + OFF_WO),   attn_out_b,
                                            (const unsigned short*)(ws + OFF_W0P), mlp_b0,
                                            (const unsigned short*)(ws + OFF_W1P), mlp_b1,
                                            out_W, out_b, out);
}

// Round 14
// 296.465 us; speedup vs baseline: 1.0073x; 1.0073x over previous
//
#include <hip/hip_runtime.h>
#include <hip/hip_bf16.h>

#define BB 2048
#define TT 128
#define NN (BB*TT)          // 262144
#define NVAL NN

// workspace layout (float offsets)
#define OFF_W0P   2048u       // W0 A-frag pack (16384 bf16)
#define OFF_W1P   10240u      // W1 A-frag pack, k-permuted (65536 bf16)
#define OFF_WQKV  43008u      // attn_in_w B-frag pack
#define OFF_WO    44544u      // attn_out_w B-frag pack
#define OFF_PWHA  49792u      // air Whh f16 A-frag pack (perm rows, exp2-scaled): 1536 uints
#define OFF_PWHM  51328u      // m   Whh f16 A-frag pack: 1536 uints
#define OFF_PWCA  52864u      // air combined Wih f16 A-frag pack (+bias col): 1536 uints
#define OFF_PWCM  54400u      // m   combined Wih f16 A-frag pack: 1536 uints
#define OFF_BHNA  55936u      // air bhh n-gate (32 f32, x 2*log2e)
#define OFF_BHNM  55968u      // m   bhh n-gate (32 f32)
#define OFF_AIRF  83968u      // air_feat bf16: NN*32 shorts = 4194304 floats
#define OFF_MF    4278272u    // m_feat bf16: 2*NN*32 shorts = 8388608 floats
#define OFF_MASK  12666880u   // N*2 mask floats

#define L2E 1.44269504088896341f

typedef __attribute__((ext_vector_type(8))) short short8;
typedef __attribute__((ext_vector_type(4))) float f32x4;
typedef _Float16 f16x8 __attribute__((ext_vector_type(8)));
typedef unsigned u32x4 __attribute__((ext_vector_type(4)));

__device__ __forceinline__ unsigned short f2bf(float f) {
    unsigned u = __builtin_bit_cast(unsigned, f);
    u += 0x7FFFu + ((u >> 16) & 1u);       // RNE
    return (unsigned short)(u >> 16);
}
__device__ __forceinline__ unsigned f2h(float f) {
    _Float16 h = (_Float16)f;
    return (unsigned)__builtin_bit_cast(unsigned short, h);
}
__device__ __forceinline__ unsigned pkh2(float a, float b) {
    return (f2h(b) << 16) | f2h(a);
}
__device__ __forceinline__ float fast_rcp(float x) {
    return __builtin_amdgcn_rcpf(x);
}
__device__ __forceinline__ float ex2(float x) {
    return __builtin_amdgcn_exp2f(x);
}
__device__ __forceinline__ unsigned cvt_pk_bf16(float a, float b) {
    unsigned r;
    asm("v_cvt_pk_bf16_f32 %0, %1, %2" : "=v"(r) : "v"(a), "v"(b));
    return r;
}
__device__ __forceinline__ f32x4 mfma16f(f16x8 a, f16x8 b, f32x4 c) {
    return __builtin_amdgcn_mfma_f32_16x16x32_f16(a, b, c, 0, 0, 0);
}
__device__ __forceinline__ f32x4 mfma16b(short8 a, short8 b, f32x4 c) {
    return __builtin_amdgcn_mfma_f32_16x16x32_bf16(a, b, c, 0, 0, 0);
}
__device__ __forceinline__ float lrelu(float h) {
    return (h > 0.f) ? h : 0.01f*h;
}

// ---------------- prep -----------------------------------------------------
__global__ __launch_bounds__(256) void prep_kernel(
    const float* __restrict__ enc_air_W, const float* __restrict__ enc_air_b,
    const float* __restrict__ enc_m_W,   const float* __restrict__ enc_m_b,
    const float* __restrict__ air_Wih,   const float* __restrict__ air_bih,
    const float* __restrict__ m_Wih,     const float* __restrict__ m_bih,
    const float* __restrict__ air_Whh,   const float* __restrict__ m_Whh,
    const float* __restrict__ air_bhh,   const float* __restrict__ m_bhh,
    const float* __restrict__ W0,        const float* __restrict__ W1,
    const float* __restrict__ attn_in_w, const float* __restrict__ attn_out_w,
    float* __restrict__ ws)
{
    int b = blockIdx.x, t = threadIdx.x;
    if (b == 0) {
        // combined biases folded into the f16 Wc packs (b==43); idle
    } else if (b <= 32) {
        // W1 A-frag pack, K-PERMUTED for the register-native l1->l2 handoff
        unsigned short* w1p = (unsigned short*)(ws + OFF_W1P);
        int base = ((b-1)*256 + t);
        int lane = base & 63;
        int ctf  = base >> 6;           // 0..127
        int ft2  = ctf & 15, kap = ctf >> 4;
        int col = lane & 15, quad = lane >> 4;
        int o  = ft2*16 + col;
        #pragma unroll
        for (int j = 0; j < 8; j++) {
            int f = (2*kap + (j>>2))*16 + quad*4 + (j&3);
            w1p[base*8 + j] = f2bf(W1[o*256 + f]);
        }
    } else if (b <= 40) {
        // W0 A-frag pack (natural)
        unsigned short* w0p = (unsigned short*)(ws + OFF_W0P);
        int base = ((b-33)*256 + t);
        int lane = base & 63;
        int ctf  = base >> 6;
        int ct   = ctf & 15, s = ctf >> 4;   // s 0..1
        int col = lane & 15, quad = lane >> 4;
        int k0 = s*32 + quad*8;
        int o  = ct*16 + col;
        #pragma unroll
        for (int j = 0; j < 8; j++)
            w0p[base*8 + j] = f2bf(W0[o*64 + k0 + j]);
    } else if (b == 41) { // attention weight packs
        unsigned short* wqkv = (unsigned short*)(ws + OFF_WQKV);
        unsigned short* wop  = (unsigned short*)(ws + OFF_WO);
        for (int slot = t; slot < 512; slot += 256) {
            if (slot < 384) {
                int ct = slot >> 6, lane = slot & 63;
                int col = lane & 15, quad = lane >> 4;
                int o = ct*16 + col;
                #pragma unroll
                for (int j = 0; j < 8; j++)
                    wqkv[slot*8 + j] = f2bf(attn_in_w[o*32 + quad*8 + j]);
            } else {
                int s2 = slot - 384;
                int ct = s2 >> 6, lane = s2 & 63;
                int col = lane & 15, quad = lane >> 4;
                #pragma unroll
                for (int j = 0; j < 8; j++)
                    wop[s2*8 + j] = f2bf(attn_out_w[(ct*16+col)*32 + quad*8 + j]);
            }
        }
    } else if (b == 42) {
        // Whh f16 A-frag packs (exp2-prescaled: r,z x log2e; n x 2*log2e).
        unsigned* pa = (unsigned*)(ws + OFF_PWHA);
        unsigned* pm = (unsigned*)(ws + OFF_PWHM);
        for (int s = t; s < 3072; s += 256) {
            int s2 = (s < 1536) ? s : s - 1536;
            const float* W = (s < 1536) ? air_Whh : m_Whh;
            unsigned* dst = (s < 1536) ? pa : pm;
            int tile = s2 >> 8;          // 0..5
            int l    = (s2 >> 2) & 63;
            int d    = s2 & 3;           // dword within frag
            int gate = tile >> 1, hfp = tile & 1;
            int rr = l & 15;
            int f  = (rr >> 2)*8 + hfp*4 + (rr & 3);
            int k  = (l >> 4)*8 + d*2;
            int row = gate*32 + f;
            float sc = (gate == 2) ? 2.f*L2E : L2E;
            dst[s2] = pkh2(W[row*32 + k]*sc, W[row*32 + k + 1]*sc);
        }
    } else { // b == 43: combined input-weight f16 A-frags (+bias col), exp2-prescaled
        unsigned* pa = (unsigned*)(ws + OFF_PWCA);
        unsigned* pm = (unsigned*)(ws + OFF_PWCM);
        for (int s = t; s < 3072; s += 256) {
            bool isA = (s < 1536);
            int s2 = isA ? s : s - 1536;
            unsigned* dst = isA ? pa : pm;
            int tile = s2 >> 8, l = (s2 >> 2) & 63, d = s2 & 3;
            int gate = tile >> 1, hfp = tile & 1;
            int rr = l & 15;
            int f = (rr >> 2)*8 + hfp*4 + (rr & 3);
            int o = gate*32 + f;
            int kb = (l >> 4)*8 + d*2;
            int ni = isA ? 7 : 4;
            float sc = (gate == 2) ? 2.f*L2E : L2E;
            float v[2];
            #pragma unroll
            for (int e = 0; e < 2; e++) {
                int k = kb + e;
                float acc = 0.f;
                if (k < ni) {
                    for (int m = 0; m < 32; m++)
                        acc += isA ? air_Wih[o*32+m]*enc_air_W[m*7+k]
                                   : m_Wih[o*32+m]*enc_m_W[m*4+k];
                } else if (k == ni) {
                    acc = isA ? air_bih[o] : m_bih[o];
                    for (int m = 0; m < 32; m++)
                        acc += isA ? air_Wih[o*32+m]*enc_air_b[m]
                                   : m_Wih[o*32+m]*enc_m_b[m];
                    if (gate < 2) acc += isA ? air_bhh[o] : m_bhh[o]; // r,z: fold bhh
                }
                v[e] = acc*sc;
            }
            dst[s2] = pkh2(v[0], v[1]);
        }
        if (t < 32) {
            ws[OFF_BHNA + t] = air_bhh[64 + t]*2.f*L2E;
            ws[OFF_BHNM + t] = m_bhh[64 + t]*2.f*L2E;
        }
    }
}

// ---------------- GRU v7 (best measured): 2x-unrolled serial loop -----------
template<bool AIRT>
__device__ __forceinline__ void gru_tile(
    const float* __restrict__ obs, const float* __restrict__ rnn,
    const float* __restrict__ ws,
    unsigned short* __restrict__ feat, float* __restrict__ mask_f,
    float* __restrict__ nh_out, int tileIdx, unsigned* __restrict__ XH)
{
    const int lane = threadIdx.x & 63;
    const int col = lane & 15, quad = lane >> 4;

    const unsigned* pw = (const unsigned*)(ws + (AIRT ? OFF_PWHA : OFF_PWHM));
    const unsigned* pc = (const unsigned*)(ws + (AIRT ? OFF_PWCA : OFF_PWCM));
    f16x8 whf[6], wcf[6];
    #pragma unroll
    for (int i6 = 0; i6 < 6; i6++) {
        whf[i6] = __builtin_bit_cast(f16x8, *(const u32x4*)(pw + i6*256 + lane*4));
        wcf[i6] = __builtin_bit_cast(f16x8, *(const u32x4*)(pc + i6*256 + lane*4));
    }
    const float* bhnp = ws + (AIRT ? OFF_BHNA : OFF_BHNM) + quad*8;
    f32x4 bhn0 = *(const f32x4*)(bhnp);
    f32x4 bhn1 = *(const f32x4*)(bhnp + 4);

    int slot = 0, tb;
    if (AIRT) { tb = tileIdx*16; }
    else      { slot = tileIdx >> 7; tb = (tileIdx & 127)*16; }

    {
        const int coff = AIRT ? 8 : slot*4;
        #pragma unroll 4
        for (int it = 0; it < 32; it++) {
            int s = it*64 + lane;
            int r = s >> 7, t = s & 127;
            const float* p = obs + (size_t)(tb + r)*1920 + t*15 + coff;
            unsigned d0, d1, d2, d3;
            if (AIRT) {
                d0 = pkh2(p[0], p[1]); d1 = pkh2(p[2], p[3]);
                d2 = pkh2(p[4], p[5]); d3 = pkh2(p[6], 1.0f);
            } else {
                float x0 = p[0], x1 = p[1], x2 = p[2], x3 = p[3];
                d0 = pkh2(x0, x1); d1 = pkh2(x2, x3);
                d2 = 0x00003C00u; d3 = 0u;     // (1.0h, 0) bias col
                bool ok = (fabsf(x0 - 1.f) <= 1.00001e-5f) && (fabsf(x1) <= 1e-8f) &&
                          (fabsf(x2 - 1.f) <= 1.00001e-5f) && (fabsf(x3) <= 1e-8f);
                mask_f[((size_t)(tb + r)*TT + t)*2 + slot] = ok ? 1.f : 0.f;
            }
            unsigned off = (unsigned)(r*512 + 4*(t ^ (r & 7)));   // 16B XOR swizzle
            *(u32x4*)(XH + off) = (u32x4){d0, d1, d2, d3};
        }
    }
    __syncthreads();

    int rowi = tileIdx*16 + col;
    int hbase;
    if (AIRT) hbase = rowi*96;
    else      hbase = (rowi >> 1)*96 + 32 + (rowi & 1)*32;
    unsigned short* featp = feat + (size_t)rowi*(TT*32) + quad*8;

    f32x4 h0v = *(const f32x4*)(rnn + hbase + quad*8);
    f32x4 h1v = *(const f32x4*)(rnn + hbase + quad*8 + 4);

    const int xk = col & 7;
    const unsigned bidx = (unsigned)col*512;
    const f32x4 z4 = {0.f, 0.f, 0.f, 0.f};

    f32x4 gx0, gx1, gx2, gx3, gx4, gx5;
    {
        u32x4 xc = *(const u32x4*)(XH + bidx + 4u*(unsigned)(0 ^ xk));
        f16x8 xf = __builtin_bit_cast(f16x8, xc);
        gx0 = mfma16f(wcf[0], xf, z4); gx1 = mfma16f(wcf[1], xf, z4);
        gx2 = mfma16f(wcf[2], xf, z4); gx3 = mfma16f(wcf[3], xf, z4);
        gx4 = mfma16f(wcf[4], xf, z4); gx5 = mfma16f(wcf[5], xf, z4);
    }
    u32x4 xA = *(const u32x4*)(XH + bidx + 4u*(unsigned)(1 ^ xk));
    u32x4 xB = *(const u32x4*)(XH + bidx + 4u*(unsigned)(2 ^ xk));

    #pragma unroll 1
    for (int t = 0; t < TT; t += 2) {
        f32x4 gy0, gy1, gy2, gy3, gy4, gy5;
        {
            u32x4 hdv;
            hdv[0] = pkh2(h0v[0], h0v[1]); hdv[1] = pkh2(h0v[2], h0v[3]);
            hdv[2] = pkh2(h1v[0], h1v[1]); hdv[3] = pkh2(h1v[2], h1v[3]);
            f16x8 hff = __builtin_bit_cast(f16x8, hdv);

            f32x4 aR0 = mfma16f(whf[0], hff, gx0);
            f32x4 aR1 = mfma16f(whf[1], hff, gx1);
            f32x4 aZ0 = mfma16f(whf[2], hff, gx2);
            f32x4 aZ1 = mfma16f(whf[3], hff, gx3);
            f32x4 aHN0 = mfma16f(whf[4], hff, bhn0);
            f32x4 aHN1 = mfma16f(whf[5], hff, bhn1);
            f32x4 aXN0 = gx4, aXN1 = gx5;

            f16x8 xf1 = __builtin_bit_cast(f16x8, xA);
            gy0 = mfma16f(wcf[0], xf1, z4); gy1 = mfma16f(wcf[1], xf1, z4);
            gy2 = mfma16f(wcf[2], xf1, z4); gy3 = mfma16f(wcf[3], xf1, z4);
            gy4 = mfma16f(wcf[4], xf1, z4); gy5 = mfma16f(wcf[5], xf1, z4);
            const int tp = (t+3 < TT) ? t+3 : TT-1;
            xA = *(const u32x4*)(XH + bidx + 4u*(unsigned)(tp ^ xk));

            #pragma unroll
            for (int s = 0; s < 4; s++) {
                {
                    float r = fast_rcp(1.f + ex2(-aR0[s]));
                    float z = fast_rcp(1.f + ex2(-aZ0[s]));
                    float p = aXN0[s] + r*aHN0[s];
                    float n = fmaf(-2.f, fast_rcp(1.f + ex2(p)), 1.f);
                    h0v[s] = n + z*(h0v[s] - n);
                }
                {
                    float r = fast_rcp(1.f + ex2(-aR1[s]));
                    float z = fast_rcp(1.f + ex2(-aZ1[s]));
                    float p = aXN1[s] + r*aHN1[s];
                    float n = fmaf(-2.f, fast_rcp(1.f + ex2(p)), 1.f);
                    h1v[s] = n + z*(h1v[s] - n);
                }
            }

            u32x4 fwE;
            fwE[0] = cvt_pk_bf16(h0v[0], h0v[1]); fwE[1] = cvt_pk_bf16(h0v[2], h0v[3]);
            fwE[2] = cvt_pk_bf16(h1v[0], h1v[1]); fwE[3] = cvt_pk_bf16(h1v[2], h1v[3]);
            *(u32x4*)(featp + (size_t)t*32) = fwE;
        }
        {
            u32x4 hdv2;
            hdv2[0] = pkh2(h0v[0], h0v[1]); hdv2[1] = pkh2(h0v[2], h0v[3]);
            hdv2[2] = pkh2(h1v[0], h1v[1]); hdv2[3] = pkh2(h1v[2], h1v[3]);
            f16x8 hff2 = __builtin_bit_cast(f16x8, hdv2);

            f32x4 bR0 = mfma16f(whf[0], hff2, gy0);
            f32x4 bR1 = mfma16f(whf[1], hff2, gy1);
            f32x4 bZ0 = mfma16f(whf[2], hff2, gy2);
            f32x4 bZ1 = mfma16f(whf[3], hff2, gy3);
            f32x4 bHN0 = mfma16f(whf[4], hff2, bhn0);
            f32x4 bHN1 = mfma16f(whf[5], hff2, bhn1);
            f32x4 bXN0 = gy4, bXN1 = gy5;

            f16x8 xf2 = __builtin_bit_cast(f16x8, xB);
            gx0 = mfma16f(wcf[0], xf2, z4); gx1 = mfma16f(wcf[1], xf2, z4);
            gx2 = mfma16f(wcf[2], xf2, z4); gx3 = mfma16f(wcf[3], xf2, z4);
            gx4 = mfma16f(wcf[4], xf2, z4); gx5 = mfma16f(wcf[5], xf2, z4);
            const int tq = (t+4 < TT) ? t+4 : TT-1;
            xB = *(const u32x4*)(XH + bidx + 4u*(unsigned)(tq ^ xk));

            #pragma unroll
            for (int s = 0; s < 4; s++) {
                {
                    float r = fast_rcp(1.f + ex2(-bR0[s]));
                    float z = fast_rcp(1.f + ex2(-bZ0[s]));
                    float p = bXN0[s] + r*bHN0[s];
                    float n = fmaf(-2.f, fast_rcp(1.f + ex2(p)), 1.f);
                    h0v[s] = n + z*(h0v[s] - n);
                }
                {
                    float r = fast_rcp(1.f + ex2(-bR1[s]));
                    float z = fast_rcp(1.f + ex2(-bZ1[s]));
                    float p = bXN1[s] + r*bHN1[s];
                    float n = fmaf(-2.f, fast_rcp(1.f + ex2(p)), 1.f);
                    h1v[s] = n + z*(h1v[s] - n);
                }
            }

            u32x4 fwO;
            fwO[0] = cvt_pk_bf16(h0v[0], h0v[1]); fwO[1] = cvt_pk_bf16(h0v[2], h0v[3]);
            fwO[2] = cvt_pk_bf16(h1v[0], h1v[1]); fwO[3] = cvt_pk_bf16(h1v[2], h1v[3]);
            *(u32x4*)(featp + (size_t)(t+1)*32) = fwO;
        }
    }
    *(f32x4*)(nh_out + hbase + quad*8)     = h0v;
    *(f32x4*)(nh_out + hbase + quad*8 + 4) = h1v;
}

__global__ __launch_bounds__(64, 1) void gru_kernel(
    const float* __restrict__ obs, const float* __restrict__ rnn,
    const float* __restrict__ ws,
    unsigned short* __restrict__ air_feat, unsigned short* __restrict__ m_feat,
    float* __restrict__ mask_f, float* __restrict__ nh_out)
{
    __shared__ unsigned XH[8192];   // 16 rows x 128 t x 4 dwords
    int g = blockIdx.x;
    if (g < 128) gru_tile<true >(obs, rnn, ws, air_feat, mask_f, nh_out, g, XH);
    else         gru_tile<false>(obs, rnn, ws, m_feat,  mask_f, nh_out, g - 128, XH);
}

// ---------------- fused v9 (best measured): v6 structure + sigmoid softmax --
__global__ __launch_bounds__(512, 6) void fused_kernel(
    const unsigned short* __restrict__ air_feat, const unsigned short* __restrict__ m_feat,
    const float* __restrict__ mask_f,
    const unsigned short* __restrict__ wqkv, const float* __restrict__ attn_in_b,
    const unsigned short* __restrict__ wop,  const float* __restrict__ attn_out_b,
    const unsigned short* __restrict__ w0p, const float* __restrict__ b0,
    const unsigned short* __restrict__ w1p, const float* __restrict__ b1,
    const float* __restrict__ outW, const float* __restrict__ outb,
    float* __restrict__ val)
{
    __shared__ unsigned short XB[16384];   // 32KB: l2 B-frags; CT aliases (phase1)
    __shared__ unsigned short ATPS[4096];  // 8KB: AT (phase2); PS aliases (out)

    unsigned short* CT = XB;               // attn ctx transpose (phase1 only)
    unsigned short* AT = ATPS;
    float* PS = (float*)ATPS;              // [8][64] floats, AT dead by then

    const int tid  = threadIdx.x;
    const int lane = tid & 63;
    const int wid  = tid >> 6;             // 0..7
    const int col  = lane & 15;
    const int quad = lane >> 4;
    const size_t n0 = (size_t)blockIdx.x * 64;
    const int strip = wid >> 1;            // attention strip (0..3)
    const int act   = wid & 1;             // attention ct column (0..1)
    const int rt    = wid & 3;             // l1 row-tile
    const int tbase = (wid >> 2) * 8;      // l1's 8 W0 feature-tiles

    const f32x4 z4 = {0.f, 0.f, 0.f, 0.f};
    const float C1 = 0.25f*L2E;            // score scale x log2e
    const float MB = 1e9f*L2E;             // mask magnitude x log2e

    // ---- attention: one (strip, ct) per wave; sigmoid-form 2-key softmax ---
    {
        short8 wq = *(const short8*)(wqkv + ((0+act)*64 + lane)*8);
        short8 wk = *(const short8*)(wqkv + ((2+act)*64 + lane)*8);
        short8 wv = *(const short8*)(wqkv + ((4+act)*64 + lane)*8);
        short8 bAirA = *(const short8*)(air_feat + (n0 + strip*16 + col)*32 + quad*8);
        short8 a_m1 = *(const short8*)(m_feat + (n0 + strip*16 + col)*32 + quad*8);
        short8 a_m2 = *(const short8*)(m_feat + ((size_t)NN + n0 + strip*16 + col)*32 + quad*8);

        f32x4 q  = mfma16b(bAirA, wq, z4);
        f32x4 k1 = mfma16b(a_m1, wk, z4);
        f32x4 k2 = mfma16b(a_m2, wk, z4);
        f32x4 v1 = mfma16b(a_m1, wv, z4);
        f32x4 v2 = mfma16b(a_m2, wv, z4);
        float bq = attn_in_b[act*16 + col];
        float bk = attn_in_b[32 + act*16 + col];
        float bv = attn_in_b[64 + act*16 + col];

        #pragma unroll
        for (int reg = 0; reg < 4; reg++) {
            float qq = q[reg] + bq;
            float p1 = qq * (k1[reg] + bk);
            float p2 = qq * (k2[reg] + bk);
            #pragma unroll
            for (int m = 1; m < 16; m <<= 1) {
                p1 += __shfl_xor(p1, m, 64);
                p2 += __shfl_xor(p2, m, 64);
            }
            const float* mp = mask_f + (size_t)(n0 + strip*16 + quad*4 + reg)*2;
            float m0v = mp[0], m1v = mp[1];
            // w1 = sigmoid(s1 - s2); masks enter via the difference
            float md2 = (m0v > 0.5f ? -MB : 0.f) - (m1v > 0.5f ? -MB : 0.f);
            float ny = fmaf(p2 - p1, C1, -md2);     // -L2E*(s1-s2)
            float w1 = fast_rcp(1.f + ex2(ny));
            float ctxv = fmaf(v1[reg] - v2[reg], w1, v2[reg] + bv);
            CT[(strip*16 + quad*4 + reg)*40 + act*16 + col] = f2bf(ctxv);
        }
    }
    __syncthreads();   // CT complete

    // ---- phase 2: wo+AT (waves 0-3) / l1-air (waves 4-7) -------------------
    f32x4 accL1[8];
    #pragma unroll
    for (int i = 0; i < 8; i++) accL1[i] = z4;
    short8 w0f0[8];
    #pragma unroll
    for (int i = 0; i < 8; i++)
        w0f0[i] = *(const short8*)(w0p + ((tbase + i)*64 + lane)*8);
    short8 bAirL = *(const short8*)(air_feat + (n0 + rt*16 + col)*32 + quad*8);

    if (wid < 4) {
        short8 wof0 = *(const short8*)(wop + (0*64 + lane)*8);
        short8 wof1 = *(const short8*)(wop + (1*64 + lane)*8);
        short8 a_ctx = *(const short8*)&CT[(wid*16 + col)*40 + quad*8];
        f32x4 ao0 = mfma16b(a_ctx, wof0, z4);
        f32x4 ao1 = mfma16b(a_ctx, wof1, z4);
        float bor0 = attn_out_b[col], bor1 = attn_out_b[16 + col];
        #pragma unroll
        for (int reg = 0; reg < 4; reg++) {
            const float* mp = mask_f + (size_t)(n0 + wid*16 + quad*4 + reg)*2;
            bool both = (mp[0] > 0.5f) && (mp[1] > 0.5f);
            float av0 = both ? 0.f : (ao0[reg] + bor0);
            float av1 = both ? 0.f : (ao1[reg] + bor1);
            AT[wid*1024 + (quad*4 + reg)*64 + col] = f2bf(av0);
            AT[wid*1024 + (quad*4 + reg)*64 + 16 + col] = f2bf(av1);
        }
    } else {
        #pragma unroll
        for (int i = 0; i < 8; i++)
            accL1[i] = mfma16b(w0f0[i], bAirL, accL1[i]);
    }
    __syncthreads();   // AT ready; CT dead -> XB reusable

    // ---- l1 remainder ----
    if (wid < 4) {
        #pragma unroll
        for (int i = 0; i < 8; i++)
            accL1[i] = mfma16b(w0f0[i], bAirL, accL1[i]);
    }
    {
        short8 bAttn = *(const short8*)&AT[rt*1024 + col*64 + quad*8];
        #pragma unroll
        for (int i = 0; i < 8; i++) {
            short8 w0f1 = *(const short8*)(w0p + ((16 + tbase + i)*64 + lane)*8);
            accL1[i] = mfma16b(w0f1, bAttn, accL1[i]);
        }
    }
    // ---- l1 epilogue: bias+leaky+pack -> XB B-frags (linear writes) --------
    #pragma unroll
    for (int i = 0; i < 8; i += 2) {
        int t0 = tbase + i;
        f32x4 bA = *(const f32x4*)(b0 + t0*16 + quad*4);
        f32x4 bB = *(const f32x4*)(b0 + (t0+1)*16 + quad*4);
        float a0 = lrelu(accL1[i][0]   + bA[0]), a1 = lrelu(accL1[i][1]   + bA[1]);
        float a2 = lrelu(accL1[i][2]   + bA[2]), a3 = lrelu(accL1[i][3]   + bA[3]);
        float c0 = lrelu(accL1[i+1][0] + bB[0]), c1 = lrelu(accL1[i+1][1] + bB[1]);
        float c2 = lrelu(accL1[i+1][2] + bB[2]), c3 = lrelu(accL1[i+1][3] + bB[3]);
        u32x4 w;
        w[0] = cvt_pk_bf16(a0, a1); w[1] = cvt_pk_bf16(a2, a3);
        w[2] = cvt_pk_bf16(c0, c1); w[3] = cvt_pk_bf16(c2, c3);
        int kap = t0 >> 1;
        *(u32x4*)((unsigned*)XB + ((rt*8 + kap)*64 + lane)*4) = w;
    }
    __syncthreads();   // XB ready; AT dead after bAttn read above

    // ---- l2: z4 init (v6-proven); wave owns 2 feature-tiles ----------------
    f32x4 acc2[4][2];
    #pragma unroll
    for (int r = 0; r < 4; r++)
        #pragma unroll
        for (int c = 0; c < 2; c++) acc2[r][c] = z4;
    {
        short8 w1f[2], w1n[2];
        #pragma unroll
        for (int c = 0; c < 2; c++)
            w1f[c] = *(const short8*)(w1p + ((0*16 + wid*2 + c)*64 + lane)*8);
        #pragma unroll
        for (int kap = 0; kap < 8; kap++) {
            if (kap < 7) {
                #pragma unroll
                for (int c = 0; c < 2; c++)
                    w1n[c] = *(const short8*)(w1p + (((kap+1)*16 + wid*2 + c)*64 + lane)*8);
            }
            short8 bx[4];
            #pragma unroll
            for (int r = 0; r < 4; r++)
                bx[r] = *(const short8*)&XB[((r*8 + kap)*64 + lane)*8];
            #pragma unroll
            for (int c = 0; c < 2; c++)
                #pragma unroll
                for (int r = 0; r < 4; r++)
                    acc2[r][c] = mfma16b(w1f[c], bx[r], acc2[r][c]);
            #pragma unroll
            for (int c = 0; c < 2; c++) w1f[c] = w1n[c];
        }
    }

    // ---- out layer: b1v/owv loaded after l2 (v6-proven); quad-reduce only --
    f32x4 b1v[2], owv[2];
    #pragma unroll
    for (int c = 0; c < 2; c++) {
        b1v[c] = *(const f32x4*)(b1 + (wid*2 + c)*16 + quad*4);
        owv[c] = *(const f32x4*)(outW + (wid*2 + c)*16 + quad*4);
    }
    const float outb0 = outb[0];
    #pragma unroll
    for (int r = 0; r < 4; r++) {
        float pv = 0.f;
        #pragma unroll
        for (int c = 0; c < 2; c++) {
            #pragma unroll
            for (int reg = 0; reg < 4; reg++) {
                float h = lrelu(acc2[r][c][reg] + b1v[c][reg]);
                pv += h*owv[c][reg];
            }
        }
        pv += __shfl_xor(pv, 16, 64);
        pv += __shfl_xor(pv, 32, 64);
        if (lane < 16) PS[wid*64 + r*16 + lane] = pv;
    }
    __syncthreads();
    if (tid < 64)
        val[n0 + tid] = PS[0*64 + tid] + PS[1*64 + tid] + PS[2*64 + tid] + PS[3*64 + tid]
                      + PS[4*64 + tid] + PS[5*64 + tid] + PS[6*64 + tid] + PS[7*64 + tid] + outb0;
}

// ---------------- launch ---------------------------------------------------
extern "C" void kernel_launch(void* const* d_in, const int* in_sizes, int n_in,
                              void* d_out, int out_size, void* d_ws, size_t ws_size,
                              hipStream_t stream) {
    const float* obs        = (const float*)d_in[0];
    const float* rnn        = (const float*)d_in[1];
    const float* enc_air_W  = (const float*)d_in[2];
    const float* enc_air_b  = (const float*)d_in[3];
    const float* enc_m_W    = (const float*)d_in[4];
    const float* enc_m_b    = (const float*)d_in[5];
    const float* air_Wih    = (const float*)d_in[6];
    const float* air_Whh    = (const float*)d_in[7];
    const float* air_bih    = (const float*)d_in[8];
    const float* air_bhh    = (const float*)d_in[9];
    const float* m_Wih      = (const float*)d_in[10];
    const float* m_Whh      = (const float*)d_in[11];
    const float* m_bih      = (const float*)d_in[12];
    const float* m_bhh      = (const float*)d_in[13];
    const float* attn_in_w  = (const float*)d_in[14];
    const float* attn_in_b  = (const float*)d_in[15];
    const float* attn_out_w = (const float*)d_in[16];
    const float* attn_out_b = (const float*)d_in[17];
    const float* mlp_W0     = (const float*)d_in[18];
    const float* mlp_b0     = (const float*)d_in[19];
    const float* mlp_W1     = (const float*)d_in[20];
    const float* mlp_b1     = (const float*)d_in[21];
    const float* out_W      = (const float*)d_in[22];
    const float* out_b      = (const float*)d_in[23];

    float* ws  = (float*)d_ws;
    float* out = (float*)d_out;

    prep_kernel<<<44, 256, 0, stream>>>(enc_air_W, enc_air_b, enc_m_W, enc_m_b,
                                        air_Wih, air_bih, m_Wih, m_bih,
                                        air_Whh, m_Whh, air_bhh, m_bhh,
                                        mlp_W0, mlp_W1, attn_in_w, attn_out_w, ws);

    gru_kernel<<<384, 64, 0, stream>>>(obs, rnn, ws,
                                       (unsigned short*)(ws + OFF_AIRF),
                                       (unsigned short*)(ws + OFF_MF),
                                       ws + OFF_MASK, out + NVAL);

    fused_kernel<<<NN/64, 512, 0, stream>>>((const unsigned short*)(ws + OFF_AIRF),
                                            (const unsigned short*)(ws + OFF_MF),
                                            ws + OFF_MASK,
                                            (const unsigned short*)(ws + OFF_WQKV), attn_in_b,
                                            (const unsigned short*)(ws + OFF_WO),   attn_out_b,
                                            (const unsigned short*)(ws + OFF_W0P), mlp_b0,
                                            (const unsigned short*)(ws + OFF_W1P), mlp_b1,
                                            out_W, out_b, out);
}